// Round 1
// baseline (197.560 us; speedup 1.0000x reference)
//
#include <hip/hip_runtime.h>

// MaskedLoss: mean((roi*pred - roi*true)^2), roi = expanded bbox of mask fg.
// Shapes fixed by reference: [4,1,160,160,160] fp32/fp32/int32.

namespace {
constexpr int BATCH = 4;
constexpr int DSZ = 160, HSZ = 160, WSZ = 160;
constexpr int SPATIAL = DSZ * HSZ * WSZ;      // 4,096,000 elements / batch
constexpr int QPB = SPATIAL / 4;              // 1,024,000 float4/int4 quads / batch
constexpr int P1_BLOCKS = 256;                // pass1 blocks per batch
constexpr int P3_BLOCKS = 500;                // pass3 blocks per batch (500*256*8 == QPB exactly)
constexpr int NT = 256;                       // threads per block (4 waves)
constexpr int NPART = BATCH * P3_BLOCKS;      // 2000 partial sums
constexpr int SENT_MIN = 1 << 30;
}

__device__ __forceinline__ int wred_min(int v) {
#pragma unroll
  for (int o = 32; o; o >>= 1) v = min(v, __shfl_xor(v, o));
  return v;
}
__device__ __forceinline__ int wred_max(int v) {
#pragma unroll
  for (int o = 32; o; o >>= 1) v = max(v, __shfl_xor(v, o));
  return v;
}

// ---------------- pass1: per-block fg bbox over mask ----------------
__global__ __launch_bounds__(NT) void ml_pass1(const int* __restrict__ mask,
                                               int* __restrict__ blockres) {
  const int b = blockIdx.y;
  const int4* m4 = reinterpret_cast<const int4*>(mask + (size_t)b * SPATIAL);

  int dmin = SENT_MIN, dmax = -1, hmin = SENT_MIN, hmax = -1, wmin = SENT_MIN, wmax = -1;

  for (unsigned q = blockIdx.x * NT + threadIdx.x; q < (unsigned)QPB; q += P1_BLOCKS * NT) {
    int4 v = m4[q];
    bool f0 = v.x > 0, f1 = v.y > 0, f2 = v.z > 0, f3 = v.w > 0;
    if (f0 | f1 | f2 | f3) {
      unsigned d = q / 6400u;            // 6400 quads per d-slice
      unsigned rem = q - d * 6400u;
      unsigned h = rem / 40u;            // 40 quads per h-row
      int wb = (int)(rem - h * 40u) * 4;
      dmin = min(dmin, (int)d); dmax = max(dmax, (int)d);
      hmin = min(hmin, (int)h); hmax = max(hmax, (int)h);
      int lowj  = f0 ? 0 : (f1 ? 1 : (f2 ? 2 : 3));
      int highj = f3 ? 3 : (f2 ? 2 : (f1 ? 1 : 0));
      wmin = min(wmin, wb + lowj);
      wmax = max(wmax, wb + highj);
    }
  }

  dmin = wred_min(dmin); dmax = wred_max(dmax);
  hmin = wred_min(hmin); hmax = wred_max(hmax);
  wmin = wred_min(wmin); wmax = wred_max(wmax);

  __shared__ int sred[4][6];
  const int wave = threadIdx.x >> 6, lane = threadIdx.x & 63;
  if (lane == 0) {
    sred[wave][0] = dmin; sred[wave][1] = dmax;
    sred[wave][2] = hmin; sred[wave][3] = hmax;
    sred[wave][4] = wmin; sred[wave][5] = wmax;
  }
  __syncthreads();
  if (threadIdx.x == 0) {
    int o[6];
    o[0] = min(min(sred[0][0], sred[1][0]), min(sred[2][0], sred[3][0]));
    o[1] = max(max(sred[0][1], sred[1][1]), max(sred[2][1], sred[3][1]));
    o[2] = min(min(sred[0][2], sred[1][2]), min(sred[2][2], sred[3][2]));
    o[3] = max(max(sred[0][3], sred[1][3]), max(sred[2][3], sred[3][3]));
    o[4] = min(min(sred[0][4], sred[1][4]), min(sred[2][4], sred[3][4]));
    o[5] = max(max(sred[0][5], sred[1][5]), max(sred[2][5], sred[3][5]));
    int* dst = blockres + ((size_t)b * P1_BLOCKS + blockIdx.x) * 6;
#pragma unroll
    for (int k = 0; k < 6; ++k) dst[k] = o[k];
  }
}

// ---------------- pass2: reduce per-block results -> box params ----------------
__device__ __forceinline__ void axis_box(int mni, int mxi, int sh, int* lo_i, int* hi_i) {
  // replicate reference fp32 arithmetic exactly
  float mn = (float)mni, mx = (float)mxi;
  float c = (mx + mn) * 0.5f;
  float e = (mx - mn + 1.0f) * 0.5f * 1.2f;   // EXPAND = 1.2f
  float lo = fmaxf(0.0f, floorf(c - e));
  float hi = fminf((float)(sh - 1), floorf(c + e));  // hi is EXCLUSIVE bound
  *lo_i = (int)lo;
  *hi_i = (int)hi;
}

__global__ __launch_bounds__(NT) void ml_pass2(const int* __restrict__ blockres,
                                               int* __restrict__ boxp) {
  const int b = blockIdx.x;
  const int* r = blockres + ((size_t)b * P1_BLOCKS + threadIdx.x) * 6;
  int dmin = r[0], dmax = r[1], hmin = r[2], hmax = r[3], wmin = r[4], wmax = r[5];

  dmin = wred_min(dmin); dmax = wred_max(dmax);
  hmin = wred_min(hmin); hmax = wred_max(hmax);
  wmin = wred_min(wmin); wmax = wred_max(wmax);

  __shared__ int sred[4][6];
  const int wave = threadIdx.x >> 6, lane = threadIdx.x & 63;
  if (lane == 0) {
    sred[wave][0] = dmin; sred[wave][1] = dmax;
    sred[wave][2] = hmin; sred[wave][3] = hmax;
    sred[wave][4] = wmin; sred[wave][5] = wmax;
  }
  __syncthreads();
  if (threadIdx.x == 0) {
    int Dm = min(min(sred[0][0], sred[1][0]), min(sred[2][0], sred[3][0]));
    int DM = max(max(sred[0][1], sred[1][1]), max(sred[2][1], sred[3][1]));
    int Hm = min(min(sred[0][2], sred[1][2]), min(sred[2][2], sred[3][2]));
    int HM = max(max(sred[0][3], sred[1][3]), max(sred[2][3], sred[3][3]));
    int Wm = min(min(sred[0][4], sred[1][4]), min(sred[2][4], sred[3][4]));
    int WM = max(max(sred[0][5], sred[1][5]), max(sred[2][5], sred[3][5]));
    int out[6];
    if (DM < 0) {  // no foreground in this batch item -> empty box, all W_OUT
      out[0] = 0; out[1] = 0; out[2] = 0; out[3] = 0; out[4] = 0; out[5] = 0;
    } else {
      axis_box(Dm, DM, DSZ, &out[0], &out[1]);
      axis_box(Hm, HM, HSZ, &out[2], &out[3]);
      axis_box(Wm, WM, WSZ, &out[4], &out[5]);
    }
    int* dst = boxp + b * 8;
#pragma unroll
    for (int k = 0; k < 6; ++k) dst[k] = out[k];
  }
}

// ---------------- pass3: weighted squared-diff partial sums ----------------
__global__ __launch_bounds__(NT) void ml_pass3(const float* __restrict__ pred,
                                               const float* __restrict__ tru,
                                               const int* __restrict__ boxp,
                                               float* __restrict__ partials) {
  const int b = blockIdx.y;
  const int lod = boxp[b * 8 + 0], hid = boxp[b * 8 + 1];
  const int loh = boxp[b * 8 + 2], hih = boxp[b * 8 + 3];
  const int low = boxp[b * 8 + 4], hiw = boxp[b * 8 + 5];

  const float4* p4 = reinterpret_cast<const float4*>(pred + (size_t)b * SPATIAL);
  const float4* t4 = reinterpret_cast<const float4*>(tru + (size_t)b * SPATIAL);

  float s = 0.0f;
  unsigned q = blockIdx.x * NT + threadIdx.x;
#pragma unroll 4
  for (int i = 0; i < 8; ++i, q += P3_BLOCKS * NT) {   // 500*256*8 == QPB exactly
    float4 pv = p4[q];
    float4 tv = t4[q];
    unsigned d = q / 6400u;
    unsigned rem = q - d * 6400u;
    unsigned h = rem / 40u;
    int wb = (int)(rem - h * 40u) * 4;
    bool dh = ((int)d >= lod) & ((int)d < hid) & ((int)h >= loh) & ((int)h < hih);
    float r0 = (dh & (wb + 0 >= low) & (wb + 0 < hiw)) ? 1.0f : 0.1f;
    float r1 = (dh & (wb + 1 >= low) & (wb + 1 < hiw)) ? 1.0f : 0.1f;
    float r2 = (dh & (wb + 2 >= low) & (wb + 2 < hiw)) ? 1.0f : 0.1f;
    float r3 = (dh & (wb + 3 >= low) & (wb + 3 < hiw)) ? 1.0f : 0.1f;
    float a;
    a = r0 * pv.x - r0 * tv.x; s = fmaf(a, a, s);
    a = r1 * pv.y - r1 * tv.y; s = fmaf(a, a, s);
    a = r2 * pv.z - r2 * tv.z; s = fmaf(a, a, s);
    a = r3 * pv.w - r3 * tv.w; s = fmaf(a, a, s);
  }

#pragma unroll
  for (int o = 32; o; o >>= 1) s += __shfl_xor(s, o);
  __shared__ float ls[4];
  const int wave = threadIdx.x >> 6, lane = threadIdx.x & 63;
  if (lane == 0) ls[wave] = s;
  __syncthreads();
  if (threadIdx.x == 0)
    partials[(size_t)b * P3_BLOCKS + blockIdx.x] = ls[0] + ls[1] + ls[2] + ls[3];
}

// ---------------- final: sum partials, write mean ----------------
__global__ __launch_bounds__(NT) void ml_final(const float* __restrict__ partials,
                                               float* __restrict__ out) {
  double s = 0.0;
  for (int i = threadIdx.x; i < NPART; i += NT) s += (double)partials[i];
#pragma unroll
  for (int o = 32; o; o >>= 1) s += __shfl_xor(s, o);
  __shared__ double ls[4];
  const int wave = threadIdx.x >> 6, lane = threadIdx.x & 63;
  if (lane == 0) ls[wave] = s;
  __syncthreads();
  if (threadIdx.x == 0)
    out[0] = (float)((ls[0] + ls[1] + ls[2] + ls[3]) / (double)((size_t)BATCH * SPATIAL));
}

extern "C" void kernel_launch(void* const* d_in, const int* in_sizes, int n_in,
                              void* d_out, int out_size, void* d_ws, size_t ws_size,
                              hipStream_t stream) {
  const float* y_pred = (const float*)d_in[0];
  const float* y_true = (const float*)d_in[1];
  const int*   mask   = (const int*)d_in[2];
  float* out = (float*)d_out;

  char* ws = (char*)d_ws;
  int*   blockres = (int*)(ws);                 // 4*256*6 ints   = 24,576 B
  int*   boxp     = (int*)(ws + 32768);         // 4*8 ints       = 128 B
  float* partials = (float*)(ws + 36864);       // 2000 floats    = 8,000 B

  ml_pass1<<<dim3(P1_BLOCKS, BATCH), NT, 0, stream>>>(mask, blockres);
  ml_pass2<<<dim3(BATCH), NT, 0, stream>>>(blockres, boxp);
  ml_pass3<<<dim3(P3_BLOCKS, BATCH), NT, 0, stream>>>(y_pred, y_true, boxp, partials);
  ml_final<<<1, NT, 0, stream>>>(partials, out);
}

// Round 3
// 194.114 us; speedup vs baseline: 1.0178x; 1.0178x over previous
//
#include <hip/hip_runtime.h>

// MaskedLoss: mean((roi*pred - roi*true)^2), roi = expanded bbox of mask fg.
// Shapes fixed by reference: [4,1,160,160,160] fp32/fp32/int32.
//
// Key layout fact: 160*160*160 = 4,096,000 voxels = 1,024,000 int4/float4
// quads per batch; 6400 quads per d-slice, 40 quads per (d,h) row.
// Grid-stride is chosen as 128000 quads = EXACTLY 20 d-slices, so along the
// per-thread loop d advances by 20/iter and (h, w) are LOOP-INVARIANT ->
// no divisions, no h/w tests in the hot loops.

namespace {
constexpr int BATCH = 4;
constexpr int DSZ = 160, HSZ = 160, WSZ = 160;
constexpr int SPATIAL = DSZ * HSZ * WSZ;      // 4,096,000
constexpr int QPB = SPATIAL / 4;              // 1,024,000 quads / batch
constexpr int NT = 256;                       // 4 waves / block
constexpr int PB = 500;                       // blocks per batch (both passes)
constexpr int STRIDE_Q = PB * NT;             // 128000 = 20 * 6400  (20 d-slices)
constexpr int ITERS = QPB / STRIDE_Q;         // 8
constexpr int NPART = BATCH * PB;             // 2000 partials
constexpr int SENT_MIN = 1 << 30;
}

__device__ __forceinline__ int wred_min(int v) {
#pragma unroll
  for (int o = 32; o; o >>= 1) v = min(v, __shfl_xor(v, o));
  return v;
}
__device__ __forceinline__ int wred_max(int v) {
#pragma unroll
  for (int o = 32; o; o >>= 1) v = max(v, __shfl_xor(v, o));
  return v;
}

// ---------------- pass1: per-block fg bbox over mask (branch-free) ----------------
__global__ __launch_bounds__(NT) void ml_pass1(const int* __restrict__ mask,
                                               int* __restrict__ blockres) {
  const int b = blockIdx.y;
  const int4* m4 = reinterpret_cast<const int4*>(mask + (size_t)b * SPATIAL);

  const unsigned q0 = blockIdx.x * NT + threadIdx.x;   // < 128000
  const unsigned d0 = q0 / 6400u;
  const unsigned rem = q0 - d0 * 6400u;                // invariant along loop
  const unsigned h = rem / 40u;
  const int wb = (int)(rem - h * 40u) * 4;

  unsigned itermask = 0;  // bit i: any fg in iteration i (d = d0 + 20*i)
  int elemmask = 0;       // bit j: any fg at w = wb + j (any iteration)
#pragma unroll
  for (int i = 0; i < ITERS; ++i) {
    int4 v = m4[q0 + (size_t)i * STRIDE_Q];
    int e = (int)(v.x > 0) | ((int)(v.y > 0) << 1) |
            ((int)(v.z > 0) << 2) | ((int)(v.w > 0) << 3);
    elemmask |= e;
    itermask |= (e ? (1u << i) : 0u);
  }

  int dmin = SENT_MIN, dmax = -1, hmin = SENT_MIN, hmax = -1, wmin = SENT_MIN, wmax = -1;
  if (itermask) {
    int ifirst = __ffs(itermask) - 1;
    int ilast = 31 - __clz(itermask);
    dmin = (int)d0 + 20 * ifirst;
    dmax = (int)d0 + 20 * ilast;
    hmin = hmax = (int)h;
    wmin = wb + (__ffs(elemmask) - 1);
    wmax = wb + (31 - __clz(elemmask));
  }

  dmin = wred_min(dmin); dmax = wred_max(dmax);
  hmin = wred_min(hmin); hmax = wred_max(hmax);
  wmin = wred_min(wmin); wmax = wred_max(wmax);

  __shared__ int sred[4][6];
  const int wave = threadIdx.x >> 6, lane = threadIdx.x & 63;
  if (lane == 0) {
    sred[wave][0] = dmin; sred[wave][1] = dmax;
    sred[wave][2] = hmin; sred[wave][3] = hmax;
    sred[wave][4] = wmin; sred[wave][5] = wmax;
  }
  __syncthreads();
  if (threadIdx.x == 0) {
    int o[6];
    o[0] = min(min(sred[0][0], sred[1][0]), min(sred[2][0], sred[3][0]));
    o[1] = max(max(sred[0][1], sred[1][1]), max(sred[2][1], sred[3][1]));
    o[2] = min(min(sred[0][2], sred[1][2]), min(sred[2][2], sred[3][2]));
    o[3] = max(max(sred[0][3], sred[1][3]), max(sred[2][3], sred[3][3]));
    o[4] = min(min(sred[0][4], sred[1][4]), min(sred[2][4], sred[3][4]));
    o[5] = max(max(sred[0][5], sred[1][5]), max(sred[2][5], sred[3][5]));
    int* dst = blockres + ((size_t)b * PB + blockIdx.x) * 6;
#pragma unroll
    for (int k = 0; k < 6; ++k) dst[k] = o[k];
  }
}

// ---------------- pass2: reduce per-block results -> box params ----------------
__device__ __forceinline__ void axis_box(int mni, int mxi, int sh, int* lo_i, int* hi_i) {
  // replicate reference fp32 arithmetic exactly
  float mn = (float)mni, mx = (float)mxi;
  float c = (mx + mn) * 0.5f;
  float e = (mx - mn + 1.0f) * 0.5f * 1.2f;          // EXPAND = 1.2f
  float lo = fmaxf(0.0f, floorf(c - e));
  float hi = fminf((float)(sh - 1), floorf(c + e));  // hi is EXCLUSIVE bound
  *lo_i = (int)lo;
  *hi_i = (int)hi;
}

__global__ __launch_bounds__(NT) void ml_pass2(const int* __restrict__ blockres,
                                               int* __restrict__ boxp) {
  const int b = blockIdx.x;
  int dmin = SENT_MIN, dmax = -1, hmin = SENT_MIN, hmax = -1, wmin = SENT_MIN, wmax = -1;
  for (int i = threadIdx.x; i < PB; i += NT) {
    const int* r = blockres + ((size_t)b * PB + i) * 6;
    dmin = min(dmin, r[0]); dmax = max(dmax, r[1]);
    hmin = min(hmin, r[2]); hmax = max(hmax, r[3]);
    wmin = min(wmin, r[4]); wmax = max(wmax, r[5]);
  }

  dmin = wred_min(dmin); dmax = wred_max(dmax);
  hmin = wred_min(hmin); hmax = wred_max(hmax);
  wmin = wred_min(wmin); wmax = wred_max(wmax);

  __shared__ int sred[4][6];
  const int wave = threadIdx.x >> 6, lane = threadIdx.x & 63;
  if (lane == 0) {
    sred[wave][0] = dmin; sred[wave][1] = dmax;
    sred[wave][2] = hmin; sred[wave][3] = hmax;
    sred[wave][4] = wmin; sred[wave][5] = wmax;
  }
  __syncthreads();
  if (threadIdx.x == 0) {
    int Dm = min(min(sred[0][0], sred[1][0]), min(sred[2][0], sred[3][0]));
    int DM = max(max(sred[0][1], sred[1][1]), max(sred[2][1], sred[3][1]));
    int Hm = min(min(sred[0][2], sred[1][2]), min(sred[2][2], sred[3][2]));
    int HM = max(max(sred[0][3], sred[1][3]), max(sred[2][3], sred[3][3]));
    int Wm = min(min(sred[0][4], sred[1][4]), min(sred[2][4], sred[3][4]));
    int WM = max(max(sred[0][5], sred[1][5]), max(sred[2][5], sred[3][5]));
    int out[6];
    if (DM < 0) {  // no foreground -> empty box, all W_OUT
      out[0] = 0; out[1] = 0; out[2] = 0; out[3] = 0; out[4] = 0; out[5] = 0;
    } else {
      axis_box(Dm, DM, DSZ, &out[0], &out[1]);
      axis_box(Hm, HM, HSZ, &out[2], &out[3]);
      axis_box(Wm, WM, WSZ, &out[4], &out[5]);
    }
    int* dst = boxp + b * 8;
#pragma unroll
    for (int k = 0; k < 6; ++k) dst[k] = out[k];
  }
}

// ---------------- pass3: weighted squared-diff partial sums ----------------
__global__ __launch_bounds__(NT) void ml_pass3(const float* __restrict__ pred,
                                               const float* __restrict__ tru,
                                               const int* __restrict__ boxp,
                                               float* __restrict__ partials) {
  const int b = blockIdx.y;
  const int lod = boxp[b * 8 + 0], hid = boxp[b * 8 + 1];
  const int loh = boxp[b * 8 + 2], hih = boxp[b * 8 + 3];
  const int low = boxp[b * 8 + 4], hiw = boxp[b * 8 + 5];

  const float4* p4 = reinterpret_cast<const float4*>(pred + (size_t)b * SPATIAL);
  const float4* t4 = reinterpret_cast<const float4*>(tru + (size_t)b * SPATIAL);

  const unsigned q0 = blockIdx.x * NT + threadIdx.x;   // < 128000
  const unsigned d0 = q0 / 6400u;
  const unsigned rem = q0 - d0 * 6400u;                // invariant along loop
  const unsigned h = rem / 40u;
  const int wb = (int)(rem - h * 40u) * 4;

  // fold the (h,w) membership into per-element weights once; only the d test
  // remains in the loop.
  const bool inh = ((int)h >= loh) & ((int)h < hih);
  const float wx = (inh & (wb + 0 >= low) & (wb + 0 < hiw)) ? 1.0f : 0.1f;
  const float wy = (inh & (wb + 1 >= low) & (wb + 1 < hiw)) ? 1.0f : 0.1f;
  const float wz = (inh & (wb + 2 >= low) & (wb + 2 < hiw)) ? 1.0f : 0.1f;
  const float ww = (inh & (wb + 3 >= low) & (wb + 3 < hiw)) ? 1.0f : 0.1f;

  float s0 = 0.0f, s1 = 0.0f, s2 = 0.0f, s3 = 0.0f;
#pragma unroll
  for (int i = 0; i < ITERS; ++i) {
    float4 pv = p4[q0 + (size_t)i * STRIDE_Q];
    float4 tv = t4[q0 + (size_t)i * STRIDE_Q];
    int d = (int)d0 + 20 * i;
    bool ind = (d >= lod) & (d < hid);
    float rx = ind ? wx : 0.1f;
    float ry = ind ? wy : 0.1f;
    float rz = ind ? wz : 0.1f;
    float rw = ind ? ww : 0.1f;
    float a;
    a = rx * pv.x - rx * tv.x; s0 = fmaf(a, a, s0);
    a = ry * pv.y - ry * tv.y; s1 = fmaf(a, a, s1);
    a = rz * pv.z - rz * tv.z; s2 = fmaf(a, a, s2);
    a = rw * pv.w - rw * tv.w; s3 = fmaf(a, a, s3);
  }
  float s = (s0 + s1) + (s2 + s3);

#pragma unroll
  for (int o = 32; o; o >>= 1) s += __shfl_xor(s, o);
  __shared__ float ls[4];
  const int wave = threadIdx.x >> 6, lane = threadIdx.x & 63;
  if (lane == 0) ls[wave] = s;
  __syncthreads();
  if (threadIdx.x == 0)
    partials[(size_t)b * PB + blockIdx.x] = ls[0] + ls[1] + ls[2] + ls[3];
}

// ---------------- final: sum partials, write mean ----------------
__global__ __launch_bounds__(NT) void ml_final(const float* __restrict__ partials,
                                               float* __restrict__ out) {
  double s = 0.0;
  for (int i = threadIdx.x; i < NPART; i += NT) s += (double)partials[i];
#pragma unroll
  for (int o = 32; o; o >>= 1) s += __shfl_xor(s, o);
  __shared__ double ls[4];
  const int wave = threadIdx.x >> 6, lane = threadIdx.x & 63;
  if (lane == 0) ls[wave] = s;
  __syncthreads();
  if (threadIdx.x == 0)
    out[0] = (float)((ls[0] + ls[1] + ls[2] + ls[3]) / (double)((size_t)BATCH * SPATIAL));
}

extern "C" void kernel_launch(void* const* d_in, const int* in_sizes, int n_in,
                              void* d_out, int out_size, void* d_ws, size_t ws_size,
                              hipStream_t stream) {
  const float* y_pred = (const float*)d_in[0];
  const float* y_true = (const float*)d_in[1];
  const int*   mask   = (const int*)d_in[2];
  float* out = (float*)d_out;

  char* ws = (char*)d_ws;
  int*   blockres = (int*)(ws);                 // 4*500*6 ints = 48,000 B
  int*   boxp     = (int*)(ws + 49152);         // 4*8 ints     = 128 B
  float* partials = (float*)(ws + 53248);       // 2000 floats  = 8,000 B

  ml_pass1<<<dim3(PB, BATCH), NT, 0, stream>>>(mask, blockres);
  ml_pass2<<<dim3(BATCH), NT, 0, stream>>>(blockres, boxp);
  ml_pass3<<<dim3(PB, BATCH), NT, 0, stream>>>(y_pred, y_true, boxp, partials);
  ml_final<<<1, NT, 0, stream>>>(partials, out);
}